// Round 4
// baseline (19284.917 us; speedup 1.0000x reference)
//
#include <hip/hip_runtime.h>
#include <hip/hip_bf16.h>

#define BATCH 8
#define SEQ   2048
#define DIM   1024
#define NLAYER 2

typedef float  f32x4 __attribute__((ext_vector_type(4)));
typedef short  s16x8 __attribute__((ext_vector_type(8)));
typedef unsigned short u16x4 __attribute__((ext_vector_type(4)));

// =====================================================================
// fp32 GEMM (bit-identical numerics; used for everything that feeds an
// RNN scan): C = alpha * (A @ op(B)) + bias
// =====================================================================
template<int TRANSB>
__global__ __launch_bounds__(256)
void gemm_f32(const float* __restrict__ A, const float* __restrict__ B,
              const float* __restrict__ bias, float* __restrict__ C,
              int M, int N, int K, float alpha,
              long long strideA, long long strideB, long long strideC)
{
  __shared__ float As[32][128];
  __shared__ float Bs[32][128];
  const int z = blockIdx.z;
  A += (size_t)z * strideA;
  B += (size_t)z * strideB;
  C += (size_t)z * strideC;

  const int tid  = threadIdx.x;
  const int row0 = blockIdx.x * 128;
  const int col0 = blockIdx.y * 128;
  const int tm   = tid >> 4;
  const int tn   = tid & 15;

  float acc[8][8];
#pragma unroll
  for (int i = 0; i < 8; ++i)
#pragma unroll
    for (int j = 0; j < 8; ++j) acc[i][j] = 0.f;

  for (int k0 = 0; k0 < K; k0 += 32) {
    __syncthreads();
    {
      const int c = tid & 7, r0 = tid >> 3;
#pragma unroll
      for (int rep = 0; rep < 4; ++rep) {
        const int r = r0 + rep * 32;
        const float4 v = *(const float4*)&A[(size_t)(row0 + r) * K + k0 + c * 4];
        As[c*4+0][r] = v.x; As[c*4+1][r] = v.y; As[c*4+2][r] = v.z; As[c*4+3][r] = v.w;
      }
    }
    if (TRANSB) {
      const int c = tid & 7, r0 = tid >> 3;
#pragma unroll
      for (int rep = 0; rep < 4; ++rep) {
        const int r = r0 + rep * 32;
        const float4 v = *(const float4*)&B[(size_t)(col0 + r) * K + k0 + c * 4];
        Bs[c*4+0][r] = v.x; Bs[c*4+1][r] = v.y; Bs[c*4+2][r] = v.z; Bs[c*4+3][r] = v.w;
      }
    } else {
      const int n4 = tid & 31, kk0 = tid >> 5;
#pragma unroll
      for (int rep = 0; rep < 4; ++rep) {
        const int kk = kk0 + rep * 8;
        const float4 v = *(const float4*)&B[(size_t)(k0 + kk) * N + col0 + n4 * 4];
        *(float4*)&Bs[kk][n4 * 4] = v;
      }
    }
    __syncthreads();

#pragma unroll
    for (int kk = 0; kk < 32; ++kk) {
      float a[8], b[8];
      *(float4*)&a[0] = *(const float4*)&As[kk][tm * 8];
      *(float4*)&a[4] = *(const float4*)&As[kk][tm * 8 + 4];
      *(float4*)&b[0] = *(const float4*)&Bs[kk][tn * 8];
      *(float4*)&b[4] = *(const float4*)&Bs[kk][tn * 8 + 4];
#pragma unroll
      for (int i = 0; i < 8; ++i)
#pragma unroll
        for (int j = 0; j < 8; ++j)
          acc[i][j] = fmaf(a[i], b[j], acc[i][j]);
    }
  }

  float bvv[8] = {0,0,0,0,0,0,0,0};
  if (bias) {
    *(float4*)&bvv[0] = *(const float4*)&bias[col0 + tn * 8];
    *(float4*)&bvv[4] = *(const float4*)&bias[col0 + tn * 8 + 4];
  }
#pragma unroll
  for (int i = 0; i < 8; ++i) {
    const size_t row = (size_t)(row0 + tm * 8 + i);
    float r[8];
#pragma unroll
    for (int j = 0; j < 8; ++j) r[j] = fmaf(alpha, acc[i][j], bvv[j]);
    *(float4*)&C[row * N + col0 + tn * 8]     = *(float4*)&r[0];
    *(float4*)&C[row * N + col0 + tn * 8 + 4] = *(float4*)&r[4];
  }
}

// =====================================================================
// bf16x3 split-precision MFMA GEMM (post-scan paths only)
// =====================================================================
__device__ __forceinline__ unsigned short bf16_rne(float x) {
  const unsigned u = __float_as_uint(x);
  return (unsigned short)((u + 0x7FFFu + ((u >> 16) & 1u)) >> 16);
}
__device__ __forceinline__ void split_bf16(float x, unsigned short& hi, unsigned short& lo) {
  hi = bf16_rne(x);
  const float hf = __uint_as_float((unsigned)hi << 16);
  lo = bf16_rne(x - hf);
}

template<int TRANSB>
__global__ __launch_bounds__(256)
void gemm_bf16x3(const float* __restrict__ A, const float* __restrict__ B,
                 const float* __restrict__ bias, float* __restrict__ C,
                 int M, int N, int K, float alpha,
                 long long strideA, long long strideB, long long strideC)
{
  constexpr int LK = 40;
  __shared__ unsigned short Ah[128 * LK], Al[128 * LK];
  __shared__ unsigned short Bh[128 * LK], Bl[128 * LK];

  const int z = blockIdx.z;
  A += (size_t)z * strideA;
  B += (size_t)z * strideB;
  C += (size_t)z * strideC;

  const int tid  = threadIdx.x;
  const int row0 = blockIdx.x * 128;
  const int col0 = blockIdx.y * 128;
  const int w    = tid >> 6;
  const int lane = tid & 63;
  const int m0   = (w >> 1) * 64;
  const int n0   = (w & 1) * 64;
  const int half = lane >> 4;
  const int mr   = lane & 15;

  f32x4 acc[4][4];
#pragma unroll
  for (int i = 0; i < 4; ++i)
#pragma unroll
    for (int j = 0; j < 4; ++j) acc[i][j] = (f32x4){0.f, 0.f, 0.f, 0.f};

  for (int k0 = 0; k0 < K; k0 += 32) {
    __syncthreads();
    {
      const int r = tid >> 3, c4 = tid & 7;
#pragma unroll
      for (int rep = 0; rep < 4; ++rep) {
        const int row = r + rep * 32;
        const float4 v = *(const float4*)&A[(size_t)(row0 + row) * K + k0 + c4 * 4];
        unsigned short h0,h1,h2,h3,l0,l1,l2,l3;
        split_bf16(v.x, h0, l0); split_bf16(v.y, h1, l1);
        split_bf16(v.z, h2, l2); split_bf16(v.w, h3, l3);
        *(u16x4*)&Ah[row * LK + c4 * 4] = (u16x4){h0, h1, h2, h3};
        *(u16x4*)&Al[row * LK + c4 * 4] = (u16x4){l0, l1, l2, l3};
      }
    }
    if (TRANSB) {
      const int r = tid >> 3, c4 = tid & 7;
#pragma unroll
      for (int rep = 0; rep < 4; ++rep) {
        const int row = r + rep * 32;
        const float4 v = *(const float4*)&B[(size_t)(col0 + row) * K + k0 + c4 * 4];
        unsigned short h0,h1,h2,h3,l0,l1,l2,l3;
        split_bf16(v.x, h0, l0); split_bf16(v.y, h1, l1);
        split_bf16(v.z, h2, l2); split_bf16(v.w, h3, l3);
        *(u16x4*)&Bh[row * LK + c4 * 4] = (u16x4){h0, h1, h2, h3};
        *(u16x4*)&Bl[row * LK + c4 * 4] = (u16x4){l0, l1, l2, l3};
      }
    } else {
      const int kk8 = tid >> 5, n4 = tid & 31;
#pragma unroll
      for (int rep = 0; rep < 4; ++rep) {
        const int kk = kk8 + rep * 8;
        const float4 v = *(const float4*)&B[(size_t)(k0 + kk) * N + col0 + n4 * 4];
        unsigned short h, l;
        split_bf16(v.x, h, l); Bh[(n4*4+0)*LK + kk] = h; Bl[(n4*4+0)*LK + kk] = l;
        split_bf16(v.y, h, l); Bh[(n4*4+1)*LK + kk] = h; Bl[(n4*4+1)*LK + kk] = l;
        split_bf16(v.z, h, l); Bh[(n4*4+2)*LK + kk] = h; Bl[(n4*4+2)*LK + kk] = l;
        split_bf16(v.w, h, l); Bh[(n4*4+3)*LK + kk] = h; Bl[(n4*4+3)*LK + kk] = l;
      }
    }
    __syncthreads();

    s16x8 ah[4], al[4], bh[4], bl[4];
#pragma unroll
    for (int i = 0; i < 4; ++i) {
      ah[i] = *(const s16x8*)&Ah[(m0 + i*16 + mr) * LK + half * 8];
      al[i] = *(const s16x8*)&Al[(m0 + i*16 + mr) * LK + half * 8];
      bh[i] = *(const s16x8*)&Bh[(n0 + i*16 + mr) * LK + half * 8];
      bl[i] = *(const s16x8*)&Bl[(n0 + i*16 + mr) * LK + half * 8];
    }
#pragma unroll
    for (int i = 0; i < 4; ++i)
#pragma unroll
      for (int j = 0; j < 4; ++j) {
        acc[i][j] = __builtin_amdgcn_mfma_f32_16x16x32_bf16(ah[i], bh[j], acc[i][j], 0, 0, 0);
        acc[i][j] = __builtin_amdgcn_mfma_f32_16x16x32_bf16(ah[i], bl[j], acc[i][j], 0, 0, 0);
        acc[i][j] = __builtin_amdgcn_mfma_f32_16x16x32_bf16(al[i], bh[j], acc[i][j], 0, 0, 0);
      }
  }

#pragma unroll
  for (int j = 0; j < 4; ++j) {
    const int col = col0 + n0 + j * 16 + mr;
    const float bb = bias ? bias[col] : 0.f;
#pragma unroll
    for (int i = 0; i < 4; ++i) {
#pragma unroll
      for (int q = 0; q < 4; ++q) {
        const int row = row0 + m0 + i * 16 + half * 4 + q;
        C[(size_t)row * N + col] = fmaf(alpha, acc[i][j][q], bb);
      }
    }
  }
}

// =====================================================================
// tanh without an OCML call (abs err ~1e-7)
// =====================================================================
__device__ __forceinline__ float fast_tanh(float x) {
  const float a = fabsf(x);
  const float e = __expf(2.0f * a);
  const float t = 1.0f - 2.0f / (e + 1.0f);
  return copysignf(t, x);
}

// =====================================================================
// RNN scan, data-as-flag protocol.
//  - Whh rows pinned into 128 VGPRs via opaque empty-asm (compiler
//    cannot sink/rematerialize loads whose result feeds volatile asm).
//  - Multi-value butterfly: fold 8 accs while reducing lanes (masks
//    1,2,4 halve acc count; 8,16,32 finish). Bit-identical tree to the
//    old 6-round/8-value butterfly; lane l<8 ends holding row bitrev3(l).
// =====================================================================
__global__ __launch_bounds__(256, 1)
void rnn_scan(const float* __restrict__ Pre, float* __restrict__ Hout,
              const float* __restrict__ Whh, const float* __restrict__ bhh)
{
  const int b    = blockIdx.x & 7;
  const int p    = blockIdx.x >> 3;
  const int wv   = threadIdx.x >> 6;
  const int lane = threadIdx.x & 63;
  const int d0   = p * 32 + wv * 8;
  // bit-reversal of low 3 bits: which acc-row this lane ends up holding
  const int fl   = ((lane & 1) << 2) | (lane & 2) | ((lane >> 2) & 1);

  const float* PreB = Pre  + (size_t)b * SEQ * DIM;
  float*       HB   = Hout + (size_t)b * SEQ * DIM;

  f32x4 w[8][4];
#pragma unroll
  for (int r = 0; r < 8; ++r)
#pragma unroll
    for (int q = 0; q < 4; ++q)
      w[r][q] = *(const f32x4*)&Whh[(size_t)(d0 + r) * DIM + q * 256 + lane * 4];
  // pin: forces the 32 loads above to stay hoisted, results live in VGPRs
#pragma unroll
  for (int r = 0; r < 8; ++r)
#pragma unroll
    for (int q = 0; q < 4; ++q)
      asm volatile("" : "+v"(w[r][q]));

  const float biasv = bhh[d0 + fl];

  for (int t = 0; t < SEQ; ++t) {
    const float pre = PreB[(size_t)t * DIM + d0 + fl];

    float acc[8] = {0,0,0,0,0,0,0,0};
    if (t > 0) {
      const float* hp = HB + (size_t)(t - 1) * DIM;
      const float* p0 = hp +   0 + lane * 4;
      const float* p1 = hp + 256 + lane * 4;
      const float* p2 = hp + 512 + lane * 4;
      const float* p3 = hp + 768 + lane * 4;
      f32x4 h0, h1, h2, h3;
      while (true) {
        asm volatile(
          "global_load_dwordx4 %0, %4, off sc0 sc1\n\t"
          "global_load_dwordx4 %1, %5, off sc0 sc1\n\t"
          "global_load_dwordx4 %2, %6, off sc0 sc1\n\t"
          "global_load_dwordx4 %3, %7, off sc0 sc1\n\t"
          "s_waitcnt vmcnt(0)"
          : "=&v"(h0), "=&v"(h1), "=&v"(h2), "=&v"(h3)
          : "v"(p0), "v"(p1), "v"(p2), "v"(p3));
        bool good = true;
#pragma unroll
        for (int j = 0; j < 4; ++j) {
          good = good && (__float_as_uint(h0[j]) != 0xFFFFFFFFu);
          good = good && (__float_as_uint(h1[j]) != 0xFFFFFFFFu);
          good = good && (__float_as_uint(h2[j]) != 0xFFFFFFFFu);
          good = good && (__float_as_uint(h3[j]) != 0xFFFFFFFFu);
        }
        if (__all(good)) break;
      }
#pragma unroll
      for (int r = 0; r < 8; ++r) {
        acc[r] = fmaf(w[r][0].x, h0.x, fmaf(w[r][0].y, h0.y,
                 fmaf(w[r][0].z, h0.z, fmaf(w[r][0].w, h0.w, acc[r]))));
        acc[r] = fmaf(w[r][1].x, h1.x, fmaf(w[r][1].y, h1.y,
                 fmaf(w[r][1].z, h1.z, fmaf(w[r][1].w, h1.w, acc[r]))));
        acc[r] = fmaf(w[r][2].x, h2.x, fmaf(w[r][2].y, h2.y,
                 fmaf(w[r][2].z, h2.z, fmaf(w[r][2].w, h2.w, acc[r]))));
        acc[r] = fmaf(w[r][3].x, h3.x, fmaf(w[r][3].y, h3.y,
                 fmaf(w[r][3].z, h3.z, fmaf(w[r][3].w, h3.w, acc[r]))));
      }
    }
    // multi-value butterfly: same pairwise tree as 6x8 full butterfly
#pragma unroll
    for (int m = 0; m < 3; ++m) {
      const int mask = 1 << m;
      const int nv   = 4 >> m;             // 4, 2, 1
      const bool up  = (lane & mask) != 0;
#pragma unroll
      for (int r = 0; r < nv; ++r) {
        const float lo = up ? acc[r + nv] : acc[r];
        const float hi = up ? acc[r] : acc[r + nv];
        acc[r] = lo + __shfl_xor(hi, mask);
      }
    }
#pragma unroll
    for (int off = 8; off < 64; off <<= 1) acc[0] += __shfl_xor(acc[0], off);

    if (lane < 8) {
      const float v = fast_tanh(pre + acc[0] + biasv);
      float* dst = HB + (size_t)t * DIM + d0 + fl;
      asm volatile("global_store_dword %0, %1, off sc0 sc1"
                   :: "v"(dst), "v"(v));
    }
  }
}

// =====================================================================
// Masked softmax, in place, one row per block
// =====================================================================
__global__ __launch_bounds__(256)
void softmax_mask(float* __restrict__ S, const unsigned char* __restrict__ mask)
{
  const size_t row = (size_t)blockIdx.y * gridDim.x + blockIdx.x;
  float* p = S + row * SEQ;
  const unsigned char* mrow = mask + row * SEQ;
  __shared__ float buf[SEQ];
  __shared__ float red[4];
  const int tid = threadIdx.x, lane = tid & 63, wv = tid >> 6;

  float mx = -1e30f;
  for (int i = tid; i < SEQ; i += 256) {
    const float v = mrow[i] ? -1e9f : p[i];
    buf[i] = v;
    mx = fmaxf(mx, v);
  }
#pragma unroll
  for (int off = 1; off < 64; off <<= 1) mx = fmaxf(mx, __shfl_xor(mx, off));
  if (lane == 0) red[wv] = mx;
  __syncthreads();
  mx = fmaxf(fmaxf(red[0], red[1]), fmaxf(red[2], red[3]));

  float s = 0.f;
  for (int i = tid; i < SEQ; i += 256) {
    const float e = __expf(buf[i] - mx);
    buf[i] = e;
    s += e;
  }
#pragma unroll
  for (int off = 1; off < 64; off <<= 1) s += __shfl_xor(s, off);
  __syncthreads();
  if (lane == 0) red[wv] = s;
  __syncthreads();
  s = red[0] + red[1] + red[2] + red[3];
  const float inv = 1.f / s;
  for (int i = tid; i < SEQ; i += 256) p[i] = buf[i] * inv;
}

// =====================================================================
extern "C" void kernel_launch(void* const* d_in, const int* in_sizes, int n_in,
                              void* d_out, int out_size, void* d_ws, size_t ws_size,
                              hipStream_t stream)
{
  (void)in_sizes; (void)n_in; (void)out_size;
  const unsigned char* mask = (const unsigned char*)d_in[0];
  const float* reps = (const float*)d_in[1];
  const float* Wih  = (const float*)d_in[2];
  const float* Whh  = (const float*)d_in[3];
  const float* bih  = (const float*)d_in[4];
  const float* bhh  = (const float*)d_in[5];
  const float* Wq   = (const float*)d_in[6];
  const float* bq   = (const float*)d_in[7];
  const float* Wk   = (const float*)d_in[8];
  const float* bk   = (const float*)d_in[9];
  const float* Wv   = (const float*)d_in[10];
  const float* bv   = (const float*)d_in[11];
  const float* Wo   = (const float*)d_in[12];
  const float* bo   = (const float*)d_in[13];
  float* out = (float*)d_out;

  char* ws = (char*)d_ws;
  float* Hb = (float*)(ws);
  float* Qb = (float*)(ws + ((size_t)64  << 20));
  float* Kb = (float*)(ws + ((size_t)128 << 20));
  float* Vb = (float*)(ws + ((size_t)192 << 20));
  float* Sb = (float*)(ws + ((size_t)256 << 20));
  const size_t needFull = ((size_t)256 << 20) + (size_t)BATCH * SEQ * SEQ * 4;
  const bool fullS = ws_size >= needFull;
  const size_t hBytes = (size_t)BATCH * SEQ * DIM * 4;

  const int M1 = BATCH * SEQ;
  const float scale = 0.03125f;
  const dim3 blk(256);
  const long long sSD = (long long)SEQ * DIM;
  const long long sSS = (long long)SEQ * SEQ;

  const float* X = reps;
  for (int l = 0; l < NLAYER; ++l) {
    const size_t wof = (size_t)l * DIM * DIM;
    const size_t bof = (size_t)l * DIM;
    float* Y = (l == NLAYER - 1) ? out : Qb;
    const bool mf = (l == NLAYER - 1);

    hipMemsetAsync(Hb, 0xFF, hBytes, stream);
    gemm_f32<1><<<dim3(M1/128, DIM/128, 1), blk, 0, stream>>>(
        X, Wih + wof, bih + bof, Kb, M1, DIM, DIM, 1.f, 0, 0, 0);
    rnn_scan<<<dim3(256), blk, 0, stream>>>(Kb, Hb, Whh + wof, bhh + bof);

    if (mf) {
      gemm_bf16x3<1><<<dim3(M1/128, DIM/128, 1), blk, 0, stream>>>(
          Hb, Wq + wof, bq + bof, Qb, M1, DIM, DIM, 1.f, 0, 0, 0);
      gemm_bf16x3<1><<<dim3(M1/128, DIM/128, 1), blk, 0, stream>>>(
          Hb, Wk + wof, bk + bof, Kb, M1, DIM, DIM, 1.f, 0, 0, 0);
      gemm_bf16x3<1><<<dim3(M1/128, DIM/128, 1), blk, 0, stream>>>(
          Hb, Wv + wof, bv + bof, Vb, M1, DIM, DIM, 1.f, 0, 0, 0);
    } else {
      gemm_f32<1><<<dim3(M1/128, DIM/128, 1), blk, 0, stream>>>(
          Hb, Wq + wof, bq + bof, Qb, M1, DIM, DIM, 1.f, 0, 0, 0);
      gemm_f32<1><<<dim3(M1/128, DIM/128, 1), blk, 0, stream>>>(
          Hb, Wk + wof, bk + bof, Kb, M1, DIM, DIM, 1.f, 0, 0, 0);
      gemm_f32<1><<<dim3(M1/128, DIM/128, 1), blk, 0, stream>>>(
          Hb, Wv + wof, bv + bof, Vb, M1, DIM, DIM, 1.f, 0, 0, 0);
    }

    if (fullS) {
      if (mf) {
        gemm_bf16x3<1><<<dim3(SEQ/128, SEQ/128, BATCH), blk, 0, stream>>>(
            Qb, Kb, nullptr, Sb, SEQ, SEQ, DIM, scale, sSD, sSD, sSS);
      } else {
        gemm_f32<1><<<dim3(SEQ/128, SEQ/128, BATCH), blk, 0, stream>>>(
            Qb, Kb, nullptr, Sb, SEQ, SEQ, DIM, scale, sSD, sSD, sSS);
      }
      softmax_mask<<<dim3(SEQ, BATCH), blk, 0, stream>>>(Sb, mask);
      if (mf) {
        gemm_bf16x3<0><<<dim3(SEQ/128, DIM/128, BATCH), blk, 0, stream>>>(
            Sb, Vb, nullptr, Hb, SEQ, DIM, SEQ, 1.f, sSS, sSD, sSD);
      } else {
        gemm_f32<0><<<dim3(SEQ/128, DIM/128, BATCH), blk, 0, stream>>>(
            Sb, Vb, nullptr, Hb, SEQ, DIM, SEQ, 1.f, sSS, sSD, sSD);
      }
    } else {
      for (int bb = 0; bb < BATCH; ++bb) {
        if (mf) {
          gemm_bf16x3<1><<<dim3(SEQ/128, SEQ/128, 1), blk, 0, stream>>>(
              Qb + (size_t)bb * sSD, Kb + (size_t)bb * sSD, nullptr, Sb,
              SEQ, SEQ, DIM, scale, 0, 0, 0);
        } else {
          gemm_f32<1><<<dim3(SEQ/128, SEQ/128, 1), blk, 0, stream>>>(
              Qb + (size_t)bb * sSD, Kb + (size_t)bb * sSD, nullptr, Sb,
              SEQ, SEQ, DIM, scale, 0, 0, 0);
        }
        softmax_mask<<<dim3(SEQ, 1), blk, 0, stream>>>(Sb, mask + (size_t)bb * sSS);
        if (mf) {
          gemm_bf16x3<0><<<dim3(SEQ/128, DIM/128, 1), blk, 0, stream>>>(
              Sb, Vb + (size_t)bb * sSD, nullptr, Hb + (size_t)bb * sSD,
              SEQ, DIM, SEQ, 1.f, 0, 0, 0);
        } else {
          gemm_f32<0><<<dim3(SEQ/128, DIM/128, 1), blk, 0, stream>>>(
              Sb, Vb + (size_t)bb * sSD, nullptr, Hb + (size_t)bb * sSD,
              SEQ, DIM, SEQ, 1.f, 0, 0, 0);
        }
      }
    }
    if (mf) {
      gemm_bf16x3<1><<<dim3(M1/128, DIM/128, 1), blk, 0, stream>>>(
          Hb, Wo + wof, bo + bof, Y, M1, DIM, DIM, 1.f, 0, 0, 0);
    } else {
      gemm_f32<1><<<dim3(M1/128, DIM/128, 1), blk, 0, stream>>>(
          Hb, Wo + wof, bo + bof, Y, M1, DIM, DIM, 1.f, 0, 0, 0);
    }
    X = Y;
  }
}

// Round 5
// 16926.602 us; speedup vs baseline: 1.1393x; 1.1393x over previous
//
#include <hip/hip_runtime.h>
#include <hip/hip_bf16.h>

#define BATCH 8
#define SEQ   2048
#define DIM   1024
#define NLAYER 2

typedef float  f32x4 __attribute__((ext_vector_type(4)));
typedef short  s16x8 __attribute__((ext_vector_type(8)));
typedef unsigned short u16x4 __attribute__((ext_vector_type(4)));

// =====================================================================
// fp32 GEMM (bit-identical numerics; used for everything that feeds an
// RNN scan): C = alpha * (A @ op(B)) + bias
// =====================================================================
template<int TRANSB>
__global__ __launch_bounds__(256)
void gemm_f32(const float* __restrict__ A, const float* __restrict__ B,
              const float* __restrict__ bias, float* __restrict__ C,
              int M, int N, int K, float alpha,
              long long strideA, long long strideB, long long strideC)
{
  __shared__ float As[32][128];
  __shared__ float Bs[32][128];
  const int z = blockIdx.z;
  A += (size_t)z * strideA;
  B += (size_t)z * strideB;
  C += (size_t)z * strideC;

  const int tid  = threadIdx.x;
  const int row0 = blockIdx.x * 128;
  const int col0 = blockIdx.y * 128;
  const int tm   = tid >> 4;
  const int tn   = tid & 15;

  float acc[8][8];
#pragma unroll
  for (int i = 0; i < 8; ++i)
#pragma unroll
    for (int j = 0; j < 8; ++j) acc[i][j] = 0.f;

  for (int k0 = 0; k0 < K; k0 += 32) {
    __syncthreads();
    {
      const int c = tid & 7, r0 = tid >> 3;
#pragma unroll
      for (int rep = 0; rep < 4; ++rep) {
        const int r = r0 + rep * 32;
        const float4 v = *(const float4*)&A[(size_t)(row0 + r) * K + k0 + c * 4];
        As[c*4+0][r] = v.x; As[c*4+1][r] = v.y; As[c*4+2][r] = v.z; As[c*4+3][r] = v.w;
      }
    }
    if (TRANSB) {
      const int c = tid & 7, r0 = tid >> 3;
#pragma unroll
      for (int rep = 0; rep < 4; ++rep) {
        const int r = r0 + rep * 32;
        const float4 v = *(const float4*)&B[(size_t)(col0 + r) * K + k0 + c * 4];
        Bs[c*4+0][r] = v.x; Bs[c*4+1][r] = v.y; Bs[c*4+2][r] = v.z; Bs[c*4+3][r] = v.w;
      }
    } else {
      const int n4 = tid & 31, kk0 = tid >> 5;
#pragma unroll
      for (int rep = 0; rep < 4; ++rep) {
        const int kk = kk0 + rep * 8;
        const float4 v = *(const float4*)&B[(size_t)(k0 + kk) * N + col0 + n4 * 4];
        *(float4*)&Bs[kk][n4 * 4] = v;
      }
    }
    __syncthreads();

#pragma unroll
    for (int kk = 0; kk < 32; ++kk) {
      float a[8], b[8];
      *(float4*)&a[0] = *(const float4*)&As[kk][tm * 8];
      *(float4*)&a[4] = *(const float4*)&As[kk][tm * 8 + 4];
      *(float4*)&b[0] = *(const float4*)&Bs[kk][tn * 8];
      *(float4*)&b[4] = *(const float4*)&Bs[kk][tn * 8 + 4];
#pragma unroll
      for (int i = 0; i < 8; ++i)
#pragma unroll
        for (int j = 0; j < 8; ++j)
          acc[i][j] = fmaf(a[i], b[j], acc[i][j]);
    }
  }

  float bvv[8] = {0,0,0,0,0,0,0,0};
  if (bias) {
    *(float4*)&bvv[0] = *(const float4*)&bias[col0 + tn * 8];
    *(float4*)&bvv[4] = *(const float4*)&bias[col0 + tn * 8 + 4];
  }
#pragma unroll
  for (int i = 0; i < 8; ++i) {
    const size_t row = (size_t)(row0 + tm * 8 + i);
    float r[8];
#pragma unroll
    for (int j = 0; j < 8; ++j) r[j] = fmaf(alpha, acc[i][j], bvv[j]);
    *(float4*)&C[row * N + col0 + tn * 8]     = *(float4*)&r[0];
    *(float4*)&C[row * N + col0 + tn * 8 + 4] = *(float4*)&r[4];
  }
}

// =====================================================================
// bf16x3 split-precision MFMA GEMM (post-scan paths only)
// =====================================================================
__device__ __forceinline__ unsigned short bf16_rne(float x) {
  const unsigned u = __float_as_uint(x);
  return (unsigned short)((u + 0x7FFFu + ((u >> 16) & 1u)) >> 16);
}
__device__ __forceinline__ void split_bf16(float x, unsigned short& hi, unsigned short& lo) {
  hi = bf16_rne(x);
  const float hf = __uint_as_float((unsigned)hi << 16);
  lo = bf16_rne(x - hf);
}

template<int TRANSB>
__global__ __launch_bounds__(256)
void gemm_bf16x3(const float* __restrict__ A, const float* __restrict__ B,
                 const float* __restrict__ bias, float* __restrict__ C,
                 int M, int N, int K, float alpha,
                 long long strideA, long long strideB, long long strideC)
{
  constexpr int LK = 40;
  __shared__ unsigned short Ah[128 * LK], Al[128 * LK];
  __shared__ unsigned short Bh[128 * LK], Bl[128 * LK];

  const int z = blockIdx.z;
  A += (size_t)z * strideA;
  B += (size_t)z * strideB;
  C += (size_t)z * strideC;

  const int tid  = threadIdx.x;
  const int row0 = blockIdx.x * 128;
  const int col0 = blockIdx.y * 128;
  const int w    = tid >> 6;
  const int lane = tid & 63;
  const int m0   = (w >> 1) * 64;
  const int n0   = (w & 1) * 64;
  const int half = lane >> 4;
  const int mr   = lane & 15;

  f32x4 acc[4][4];
#pragma unroll
  for (int i = 0; i < 4; ++i)
#pragma unroll
    for (int j = 0; j < 4; ++j) acc[i][j] = (f32x4){0.f, 0.f, 0.f, 0.f};

  for (int k0 = 0; k0 < K; k0 += 32) {
    __syncthreads();
    {
      const int r = tid >> 3, c4 = tid & 7;
#pragma unroll
      for (int rep = 0; rep < 4; ++rep) {
        const int row = r + rep * 32;
        const float4 v = *(const float4*)&A[(size_t)(row0 + row) * K + k0 + c4 * 4];
        unsigned short h0,h1,h2,h3,l0,l1,l2,l3;
        split_bf16(v.x, h0, l0); split_bf16(v.y, h1, l1);
        split_bf16(v.z, h2, l2); split_bf16(v.w, h3, l3);
        *(u16x4*)&Ah[row * LK + c4 * 4] = (u16x4){h0, h1, h2, h3};
        *(u16x4*)&Al[row * LK + c4 * 4] = (u16x4){l0, l1, l2, l3};
      }
    }
    if (TRANSB) {
      const int r = tid >> 3, c4 = tid & 7;
#pragma unroll
      for (int rep = 0; rep < 4; ++rep) {
        const int row = r + rep * 32;
        const float4 v = *(const float4*)&B[(size_t)(col0 + row) * K + k0 + c4 * 4];
        unsigned short h0,h1,h2,h3,l0,l1,l2,l3;
        split_bf16(v.x, h0, l0); split_bf16(v.y, h1, l1);
        split_bf16(v.z, h2, l2); split_bf16(v.w, h3, l3);
        *(u16x4*)&Bh[row * LK + c4 * 4] = (u16x4){h0, h1, h2, h3};
        *(u16x4*)&Bl[row * LK + c4 * 4] = (u16x4){l0, l1, l2, l3};
      }
    } else {
      const int kk8 = tid >> 5, n4 = tid & 31;
#pragma unroll
      for (int rep = 0; rep < 4; ++rep) {
        const int kk = kk8 + rep * 8;
        const float4 v = *(const float4*)&B[(size_t)(k0 + kk) * N + col0 + n4 * 4];
        unsigned short h, l;
        split_bf16(v.x, h, l); Bh[(n4*4+0)*LK + kk] = h; Bl[(n4*4+0)*LK + kk] = l;
        split_bf16(v.y, h, l); Bh[(n4*4+1)*LK + kk] = h; Bl[(n4*4+1)*LK + kk] = l;
        split_bf16(v.z, h, l); Bh[(n4*4+2)*LK + kk] = h; Bl[(n4*4+2)*LK + kk] = l;
        split_bf16(v.w, h, l); Bh[(n4*4+3)*LK + kk] = h; Bl[(n4*4+3)*LK + kk] = l;
      }
    }
    __syncthreads();

    s16x8 ah[4], al[4], bh[4], bl[4];
#pragma unroll
    for (int i = 0; i < 4; ++i) {
      ah[i] = *(const s16x8*)&Ah[(m0 + i*16 + mr) * LK + half * 8];
      al[i] = *(const s16x8*)&Al[(m0 + i*16 + mr) * LK + half * 8];
      bh[i] = *(const s16x8*)&Bh[(n0 + i*16 + mr) * LK + half * 8];
      bl[i] = *(const s16x8*)&Bl[(n0 + i*16 + mr) * LK + half * 8];
    }
#pragma unroll
    for (int i = 0; i < 4; ++i)
#pragma unroll
      for (int j = 0; j < 4; ++j) {
        acc[i][j] = __builtin_amdgcn_mfma_f32_16x16x32_bf16(ah[i], bh[j], acc[i][j], 0, 0, 0);
        acc[i][j] = __builtin_amdgcn_mfma_f32_16x16x32_bf16(ah[i], bl[j], acc[i][j], 0, 0, 0);
        acc[i][j] = __builtin_amdgcn_mfma_f32_16x16x32_bf16(al[i], bh[j], acc[i][j], 0, 0, 0);
      }
  }

#pragma unroll
  for (int j = 0; j < 4; ++j) {
    const int col = col0 + n0 + j * 16 + mr;
    const float bb = bias ? bias[col] : 0.f;
#pragma unroll
    for (int i = 0; i < 4; ++i) {
#pragma unroll
      for (int q = 0; q < 4; ++q) {
        const int row = row0 + m0 + i * 16 + half * 4 + q;
        C[(size_t)row * N + col] = fmaf(alpha, acc[i][j][q], bb);
      }
    }
  }
}

// =====================================================================
// tanh without an OCML call (abs err ~1e-7)
// =====================================================================
__device__ __forceinline__ float fast_tanh(float x) {
  const float a = fabsf(x);
  const float e = __expf(2.0f * a);
  const float t = 1.0f - 2.0f / (e + 1.0f);
  return copysignf(t, x);
}

// =====================================================================
// RNN scan, data-as-flag protocol, v3:
//  - 8 waves x 4 rows (512 thr): 64 weight VGPRs/thread -> no spill.
//  - Only wave 0 polls global h (one wave covers all 1024 floats);
//    broadcasts via double-buffered LDS; others consume after barrier.
//    Deadlock-free: wave0's poll of h_t succeeds only after all local
//    waves stored h_t, ordering their reads of buf[t&1] before wave0
//    writes buf[(t+1)&1].
//  - FMA chain order and XOR-mask reduction order (1,2,4,8,16,32,
//    same leaf partition, commutative-only changes) keep the scan
//    BIT-IDENTICAL to rounds 1-4 (absmax canary: 0.0009765625).
// =====================================================================
__global__ __launch_bounds__(512, 2)
void rnn_scan(const float* __restrict__ Pre, float* __restrict__ Hout,
              const float* __restrict__ Whh, const float* __restrict__ bhh)
{
  __shared__ __align__(16) float hbuf[2][DIM];
  const int b    = blockIdx.x & 7;
  const int p    = blockIdx.x >> 3;     // 0..31
  const int wv   = threadIdx.x >> 6;    // 0..7
  const int lane = threadIdx.x & 63;
  const int d0   = p * 32 + wv * 4;
  // bitrev2 of low 2 bits: which row this lane holds after the fold
  const int fl   = ((lane & 1) << 1) | ((lane >> 1) & 1);

  const float* PreB = Pre  + (size_t)b * SEQ * DIM;
  float*       HB   = Hout + (size_t)b * SEQ * DIM;

  f32x4 w[4][4];
#pragma unroll
  for (int r = 0; r < 4; ++r)
#pragma unroll
    for (int q = 0; q < 4; ++q)
      w[r][q] = *(const f32x4*)&Whh[(size_t)(d0 + r) * DIM + q * 256 + lane * 4];
#pragma unroll
  for (int r = 0; r < 4; ++r)
#pragma unroll
    for (int q = 0; q < 4; ++q)
      asm volatile("" : "+v"(w[r][q]));

  const float biasv = bhh[d0 + fl];

  for (int t = 0; t < SEQ; ++t) {
    const float pre = PreB[(size_t)t * DIM + d0 + fl];

    float acc[4] = {0,0,0,0};
    if (t > 0) {
      if (wv == 0) {
        const float* hp = HB + (size_t)(t - 1) * DIM;
        const float* p0 = hp +   0 + lane * 4;
        const float* p1 = hp + 256 + lane * 4;
        const float* p2 = hp + 512 + lane * 4;
        const float* p3 = hp + 768 + lane * 4;
        f32x4 g0, g1, g2, g3;
        while (true) {
          asm volatile(
            "global_load_dwordx4 %0, %4, off sc0 sc1\n\t"
            "global_load_dwordx4 %1, %5, off sc0 sc1\n\t"
            "global_load_dwordx4 %2, %6, off sc0 sc1\n\t"
            "global_load_dwordx4 %3, %7, off sc0 sc1\n\t"
            "s_waitcnt vmcnt(0)"
            : "=&v"(g0), "=&v"(g1), "=&v"(g2), "=&v"(g3)
            : "v"(p0), "v"(p1), "v"(p2), "v"(p3));
          bool good = true;
#pragma unroll
          for (int j = 0; j < 4; ++j) {
            good = good && (__float_as_uint(g0[j]) != 0xFFFFFFFFu);
            good = good && (__float_as_uint(g1[j]) != 0xFFFFFFFFu);
            good = good && (__float_as_uint(g2[j]) != 0xFFFFFFFFu);
            good = good && (__float_as_uint(g3[j]) != 0xFFFFFFFFu);
          }
          if (__all(good)) break;
        }
        *(f32x4*)&hbuf[t & 1][  0 + lane * 4] = g0;
        *(f32x4*)&hbuf[t & 1][256 + lane * 4] = g1;
        *(f32x4*)&hbuf[t & 1][512 + lane * 4] = g2;
        *(f32x4*)&hbuf[t & 1][768 + lane * 4] = g3;
      }
      __syncthreads();
      const f32x4 h0 = *(const f32x4*)&hbuf[t & 1][  0 + lane * 4];
      const f32x4 h1 = *(const f32x4*)&hbuf[t & 1][256 + lane * 4];
      const f32x4 h2 = *(const f32x4*)&hbuf[t & 1][512 + lane * 4];
      const f32x4 h3 = *(const f32x4*)&hbuf[t & 1][768 + lane * 4];
#pragma unroll
      for (int r = 0; r < 4; ++r) {
        acc[r] = fmaf(w[r][0].x, h0.x, fmaf(w[r][0].y, h0.y,
                 fmaf(w[r][0].z, h0.z, fmaf(w[r][0].w, h0.w, acc[r]))));
        acc[r] = fmaf(w[r][1].x, h1.x, fmaf(w[r][1].y, h1.y,
                 fmaf(w[r][1].z, h1.z, fmaf(w[r][1].w, h1.w, acc[r]))));
        acc[r] = fmaf(w[r][2].x, h2.x, fmaf(w[r][2].y, h2.y,
                 fmaf(w[r][2].z, h2.z, fmaf(w[r][2].w, h2.w, acc[r]))));
        acc[r] = fmaf(w[r][3].x, h3.x, fmaf(w[r][3].y, h3.y,
                 fmaf(w[r][3].z, h3.z, fmaf(w[r][3].w, h3.w, acc[r]))));
      }
    }
    // fold 4 accs over masks 1,2 (same XOR tree as before -> bit-identical)
#pragma unroll
    for (int m = 0; m < 2; ++m) {
      const int mask = 1 << m;
      const int nv   = 2 >> m;             // 2, 1
      const bool up  = (lane & mask) != 0;
#pragma unroll
      for (int r = 0; r < nv; ++r) {
        const float lo = up ? acc[r + nv] : acc[r];
        const float hi = up ? acc[r] : acc[r + nv];
        acc[r] = lo + __shfl_xor(hi, mask);
      }
    }
#pragma unroll
    for (int off = 4; off < 64; off <<= 1) acc[0] += __shfl_xor(acc[0], off);

    if (lane < 4) {
      const float v = fast_tanh(pre + acc[0] + biasv);
      float* dst = HB + (size_t)t * DIM + d0 + fl;
      asm volatile("global_store_dword %0, %1, off sc0 sc1"
                   :: "v"(dst), "v"(v));
    }
  }
}

// =====================================================================
// Masked softmax, in place, one row per block
// =====================================================================
__global__ __launch_bounds__(256)
void softmax_mask(float* __restrict__ S, const unsigned char* __restrict__ mask)
{
  const size_t row = (size_t)blockIdx.y * gridDim.x + blockIdx.x;
  float* p = S + row * SEQ;
  const unsigned char* mrow = mask + row * SEQ;
  __shared__ float buf[SEQ];
  __shared__ float red[4];
  const int tid = threadIdx.x, lane = tid & 63, wv = tid >> 6;

  float mx = -1e30f;
  for (int i = tid; i < SEQ; i += 256) {
    const float v = mrow[i] ? -1e9f : p[i];
    buf[i] = v;
    mx = fmaxf(mx, v);
  }
#pragma unroll
  for (int off = 1; off < 64; off <<= 1) mx = fmaxf(mx, __shfl_xor(mx, off));
  if (lane == 0) red[wv] = mx;
  __syncthreads();
  mx = fmaxf(fmaxf(red[0], red[1]), fmaxf(red[2], red[3]));

  float s = 0.f;
  for (int i = tid; i < SEQ; i += 256) {
    const float e = __expf(buf[i] - mx);
    buf[i] = e;
    s += e;
  }
#pragma unroll
  for (int off = 1; off < 64; off <<= 1) s += __shfl_xor(s, off);
  __syncthreads();
  if (lane == 0) red[wv] = s;
  __syncthreads();
  s = red[0] + red[1] + red[2] + red[3];
  const float inv = 1.f / s;
  for (int i = tid; i < SEQ; i += 256) p[i] = buf[i] * inv;
}

// =====================================================================
extern "C" void kernel_launch(void* const* d_in, const int* in_sizes, int n_in,
                              void* d_out, int out_size, void* d_ws, size_t ws_size,
                              hipStream_t stream)
{
  (void)in_sizes; (void)n_in; (void)out_size;
  const unsigned char* mask = (const unsigned char*)d_in[0];
  const float* reps = (const float*)d_in[1];
  const float* Wih  = (const float*)d_in[2];
  const float* Whh  = (const float*)d_in[3];
  const float* bih  = (const float*)d_in[4];
  const float* bhh  = (const float*)d_in[5];
  const float* Wq   = (const float*)d_in[6];
  const float* bq   = (const float*)d_in[7];
  const float* Wk   = (const float*)d_in[8];
  const float* bk   = (const float*)d_in[9];
  const float* Wv   = (const float*)d_in[10];
  const float* bv   = (const float*)d_in[11];
  const float* Wo   = (const float*)d_in[12];
  const float* bo   = (const float*)d_in[13];
  float* out = (float*)d_out;

  char* ws = (char*)d_ws;
  float* Hb = (float*)(ws);
  float* Qb = (float*)(ws + ((size_t)64  << 20));
  float* Kb = (float*)(ws + ((size_t)128 << 20));
  float* Vb = (float*)(ws + ((size_t)192 << 20));
  float* Sb = (float*)(ws + ((size_t)256 << 20));
  const size_t needFull = ((size_t)256 << 20) + (size_t)BATCH * SEQ * SEQ * 4;
  const bool fullS = ws_size >= needFull;
  const size_t hBytes = (size_t)BATCH * SEQ * DIM * 4;

  const int M1 = BATCH * SEQ;
  const float scale = 0.03125f;
  const dim3 blk(256);
  const long long sSD = (long long)SEQ * DIM;
  const long long sSS = (long long)SEQ * SEQ;

  const float* X = reps;
  for (int l = 0; l < NLAYER; ++l) {
    const size_t wof = (size_t)l * DIM * DIM;
    const size_t bof = (size_t)l * DIM;
    float* Y = (l == NLAYER - 1) ? out : Qb;
    const bool mf = (l == NLAYER - 1);

    hipMemsetAsync(Hb, 0xFF, hBytes, stream);
    gemm_f32<1><<<dim3(M1/128, DIM/128, 1), blk, 0, stream>>>(
        X, Wih + wof, bih + bof, Kb, M1, DIM, DIM, 1.f, 0, 0, 0);
    rnn_scan<<<dim3(256), dim3(512), 0, stream>>>(Kb, Hb, Whh + wof, bhh + bof);

    if (mf) {
      gemm_bf16x3<1><<<dim3(M1/128, DIM/128, 1), blk, 0, stream>>>(
          Hb, Wq + wof, bq + bof, Qb, M1, DIM, DIM, 1.f, 0, 0, 0);
      gemm_bf16x3<1><<<dim3(M1/128, DIM/128, 1), blk, 0, stream>>>(
          Hb, Wk + wof, bk + bof, Kb, M1, DIM, DIM, 1.f, 0, 0, 0);
      gemm_bf16x3<1><<<dim3(M1/128, DIM/128, 1), blk, 0, stream>>>(
          Hb, Wv + wof, bv + bof, Vb, M1, DIM, DIM, 1.f, 0, 0, 0);
    } else {
      gemm_f32<1><<<dim3(M1/128, DIM/128, 1), blk, 0, stream>>>(
          Hb, Wq + wof, bq + bof, Qb, M1, DIM, DIM, 1.f, 0, 0, 0);
      gemm_f32<1><<<dim3(M1/128, DIM/128, 1), blk, 0, stream>>>(
          Hb, Wk + wof, bk + bof, Kb, M1, DIM, DIM, 1.f, 0, 0, 0);
      gemm_f32<1><<<dim3(M1/128, DIM/128, 1), blk, 0, stream>>>(
          Hb, Wv + wof, bv + bof, Vb, M1, DIM, DIM, 1.f, 0, 0, 0);
    }

    if (fullS) {
      if (mf) {
        gemm_bf16x3<1><<<dim3(SEQ/128, SEQ/128, BATCH), blk, 0, stream>>>(
            Qb, Kb, nullptr, Sb, SEQ, SEQ, DIM, scale, sSD, sSD, sSS);
      } else {
        gemm_f32<1><<<dim3(SEQ/128, SEQ/128, BATCH), blk, 0, stream>>>(
            Qb, Kb, nullptr, Sb, SEQ, SEQ, DIM, scale, sSD, sSD, sSS);
      }
      softmax_mask<<<dim3(SEQ, BATCH), blk, 0, stream>>>(Sb, mask);
      if (mf) {
        gemm_bf16x3<0><<<dim3(SEQ/128, DIM/128, BATCH), blk, 0, stream>>>(
            Sb, Vb, nullptr, Hb, SEQ, DIM, SEQ, 1.f, sSS, sSD, sSD);
      } else {
        gemm_f32<0><<<dim3(SEQ/128, DIM/128, BATCH), blk, 0, stream>>>(
            Sb, Vb, nullptr, Hb, SEQ, DIM, SEQ, 1.f, sSS, sSD, sSD);
      }
    } else {
      for (int bb = 0; bb < BATCH; ++bb) {
        if (mf) {
          gemm_bf16x3<1><<<dim3(SEQ/128, SEQ/128, 1), blk, 0, stream>>>(
              Qb + (size_t)bb * sSD, Kb + (size_t)bb * sSD, nullptr, Sb,
              SEQ, SEQ, DIM, scale, 0, 0, 0);
        } else {
          gemm_f32<1><<<dim3(SEQ/128, SEQ/128, 1), blk, 0, stream>>>(
              Qb + (size_t)bb * sSD, Kb + (size_t)bb * sSD, nullptr, Sb,
              SEQ, SEQ, DIM, scale, 0, 0, 0);
        }
        softmax_mask<<<dim3(SEQ, 1), blk, 0, stream>>>(Sb, mask + (size_t)bb * sSS);
        if (mf) {
          gemm_bf16x3<0><<<dim3(SEQ/128, DIM/128, 1), blk, 0, stream>>>(
              Sb, Vb + (size_t)bb * sSD, nullptr, Hb + (size_t)bb * sSD,
              SEQ, DIM, SEQ, 1.f, 0, 0, 0);
        } else {
          gemm_f32<0><<<dim3(SEQ/128, DIM/128, 1), blk, 0, stream>>>(
              Sb, Vb + (size_t)bb * sSD, nullptr, Hb + (size_t)bb * sSD,
              SEQ, DIM, SEQ, 1.f, 0, 0, 0);
        }
      }
    }
    if (mf) {
      gemm_bf16x3<1><<<dim3(M1/128, DIM/128, 1), blk, 0, stream>>>(
          Hb, Wo + wof, bo + bof, Y, M1, DIM, DIM, 1.f, 0, 0, 0);
    } else {
      gemm_f32<1><<<dim3(M1/128, DIM/128, 1), blk, 0, stream>>>(
          Hb, Wo + wof, bo + bof, Y, M1, DIM, DIM, 1.f, 0, 0, 0);
    }
    X = Y;
  }
}